// Round 3
// baseline (221.528 us; speedup 1.0000x reference)
//
#include <hip/hip_runtime.h>

#define B_ 4
#define T_ 4096
#define I_ 512
#define E_ 16
#define K_ 1024
#define J_ 512

typedef unsigned short u16;
typedef __attribute__((ext_vector_type(4))) float floatx4;
typedef __attribute__((ext_vector_type(8))) short short8;
typedef __attribute__((ext_vector_type(4))) u16 u16x4;
typedef __attribute__((ext_vector_type(8))) u16 u16x8;

__device__ __forceinline__ u16 f2bf(float f) {
  unsigned int u = __float_as_uint(f);
  u += 0x7FFFu + ((u >> 16) & 1u);   // round-to-nearest-even
  return (u16)(u >> 16);
}

// async global->LDS, 16B per lane, dest = wave-uniform base + lane*16
__device__ __forceinline__ void gload16(const u16* g, u16* l) {
  __builtin_amdgcn_global_load_lds(
      (const __attribute__((address_space(1))) unsigned int*)(g),
      (__attribute__((address_space(3))) unsigned int*)(l),
      16, 0, 0);
}

// ---- prep 1: X fp32 -> bf16 -------------------------------------------------
__global__ __launch_bounds__(256) void cvt_x(const float* __restrict__ X,
                                             u16* __restrict__ Xb) {
  const int n4 = B_ * T_ * I_ / 4;
  int i = blockIdx.x * 256 + threadIdx.x;
  const int stride = gridDim.x * 256;
  for (; i < n4; i += stride) {
    floatx4 v = ((const floatx4*)X)[i];
    u16x4 o;
    o[0] = f2bf(v[0]); o[1] = f2bf(v[1]); o[2] = f2bf(v[2]); o[3] = f2bf(v[3]);
    ((u16x4*)Xb)[i] = o;
  }
}

// ---- prep 2: W[e][i][j] fp32 -> Wt[e][j][i] bf16 ---------------------------
__global__ __launch_bounds__(256) void transp_w(const float* __restrict__ W,
                                                u16* __restrict__ Wt) {
  __shared__ u16 tile[64][65];
  const int tid = threadIdx.x;
  const int blk = blockIdx.x;           // 16 * 8 * 8 = 1024 blocks
  const int e  = blk >> 6;
  const int bi = (blk >> 3) & 7;
  const int bj = blk & 7;
  const int i0 = bi * 64, j0 = bj * 64;

#pragma unroll
  for (int p = 0; p < 4; ++p) {
    int r = p * 16 + (tid >> 4);
    int c = (tid & 15) * 4;
    floatx4 v = *(const floatx4*)(W + ((size_t)(e * I_ + i0 + r)) * J_ + j0 + c);
    tile[r][c + 0] = f2bf(v[0]);
    tile[r][c + 1] = f2bf(v[1]);
    tile[r][c + 2] = f2bf(v[2]);
    tile[r][c + 3] = f2bf(v[3]);
  }
  __syncthreads();
#pragma unroll
  for (int p = 0; p < 2; ++p) {
    int j = p * 32 + (tid >> 3);
    int ch = tid & 7;
    u16x8 o;
#pragma unroll
    for (int s = 0; s < 8; ++s) o[s] = tile[ch * 8 + s][j];
    *(u16x8*)(Wt + ((size_t)(e * J_ + j0 + j)) * I_ + i0 + ch * 8) = o;
  }
}

// ---- main: gather + bf16 MFMA GEMM -----------------------------------------
// Per block: one 128(K-rows)x128(J-cols) output tile of one (b,e) pair.
// MFMA roles transposed: A-operand = Wt (M = J), B-operand = gathered X (N = K)
// so D rows are consecutive j -> float4 stores.
// LDS: unpadded 128x64 bf16 tiles, XOR swizzle c_lds = c_glob ^ (row&7);
// staging via global_load_lds width=16 (wave-uniform base + lane*16).
// Block swizzle: all 32 tiles of one (b,e) pair share phys%8 (XCD round-robin
// heuristic) so their re-reads hit the same per-XCD L2 instead of bouncing
// through L3. Y stores are non-temporal to keep Xb/Wt resident in L2.
__global__ __launch_bounds__(256) void gemm_gather(const u16* __restrict__ Xb,
                                                   const u16* __restrict__ Wt,
                                                   const int* __restrict__ ind,
                                                   float* __restrict__ Y) {
  __shared__ alignas(16) u16 Asf[128 * 64];   // gathered X rows (N-side)
  __shared__ alignas(16) u16 Bsf[128 * 64];   // Wt rows        (M-side)

  const int tid = threadIdx.x;
  const int phys = blockIdx.x;         // 2048
  // swizzle: xcd = phys&7; be = (idx>>5)*8 + xcd; tile = idx&31
  const int xcd  = phys & 7;
  const int idx  = phys >> 3;          // 0..255
  const int tile = idx & 31;           // 0..31
  const int be   = (idx >> 5) * 8 + xcd;  // all 32 tiles of a be share xcd
  const int n_t = tile & 3;            // J tile (fastest: A-tile reuse adjacent)
  const int m_t = tile >> 2;           // K tile
  const int e = be & 15;
  const int b = be >> 4;

  const int lane = tid & 63;
  const int wave = tid >> 6;

  // staging mapping: wave covers 8 rows x 8 chunks (16B) per instruction
  const int lr = lane >> 3;                  // row within octet
  const int cg = (lane & 7) ^ lr;            // global chunk for this lane

  const u16* agp[4];
  const u16* bgp[4];
  u16* aldst[4];
  u16* bldst[4];
#pragma unroll
  for (int q = 0; q < 4; ++q) {
    const int r = wave * 32 + q * 8 + lr;
    const int t = ind[be * K_ + m_t * 128 + r];
    agp[q] = Xb + ((size_t)(b * T_ + t)) * I_ + cg * 8;
    bgp[q] = Wt + ((size_t)(e * J_ + n_t * 128 + r)) * I_ + cg * 8;
    aldst[q] = Asf + (wave * 32 + q * 8) * 64;
    bldst[q] = Bsf + (wave * 32 + q * 8) * 64;
  }

  const int wj = (wave & 1) * 64;      // J offset of this wave's 64x64
  const int wk = (wave >> 1) * 64;     // K offset
  const int ml = lane & 15;
  const int quad = lane >> 4;

  floatx4 acc[4][4] = {};              // [iw = J blocks][ik = K blocks]

  for (int kk = 0; kk < I_; kk += 64) {
#pragma unroll
    for (int q = 0; q < 4; ++q) gload16(agp[q] + kk, aldst[q]);
#pragma unroll
    for (int q = 0; q < 4; ++q) gload16(bgp[q] + kk, bldst[q]);
    __syncthreads();                   // drains vmcnt -> LDS tiles ready
#pragma unroll
    for (int s = 0; s < 2; ++s) {      // two K=32 sub-steps
      short8 wf[4], xf[4];
      const int c = s * 4 + quad;      // 16B chunk in I-dim for this lane
#pragma unroll
      for (int i = 0; i < 4; ++i) {
        const int jr = wj + i * 16 + ml;     // Wt row (j)
        const int kr = wk + i * 16 + ml;     // X row (k)
        wf[i] = *(const short8*)&Bsf[jr * 64 + ((c ^ (jr & 7)) * 8)];
        xf[i] = *(const short8*)&Asf[kr * 64 + ((c ^ (kr & 7)) * 8)];
      }
#pragma unroll
      for (int iw = 0; iw < 4; ++iw)
#pragma unroll
        for (int ik = 0; ik < 4; ++ik)
          acc[iw][ik] = __builtin_amdgcn_mfma_f32_16x16x32_bf16(
              wf[iw], xf[ik], acc[iw][ik], 0, 0, 0);
    }
    __syncthreads();
  }

  // epilogue: D row (m) = j = quad*4 + reg -> 4 consecutive j = one float4
#pragma unroll
  for (int iw = 0; iw < 4; ++iw) {
    const int j0 = n_t * 128 + wj + iw * 16 + quad * 4;
#pragma unroll
    for (int ik = 0; ik < 4; ++ik) {
      const int k0 = m_t * 128 + wk + ik * 16 + ml;
      float* yp = Y + ((size_t)(be * K_ + k0)) * J_ + j0;
      __builtin_nontemporal_store(acc[iw][ik], (floatx4*)yp);
    }
  }
}

extern "C" void kernel_launch(void* const* d_in, const int* in_sizes, int n_in,
                              void* d_out, int out_size, void* d_ws,
                              size_t ws_size, hipStream_t stream) {
  const float* X  = (const float*)d_in[0];
  const int* ind  = (const int*)d_in[1];
  const float* W  = (const float*)d_in[2];
  float* Y = (float*)d_out;

  u16* Xb = (u16*)d_ws;                                        // 16 MiB
  u16* Wt = (u16*)((char*)d_ws + (size_t)B_ * T_ * I_ * 2);    // + 8 MiB

  cvt_x<<<2048, 256, 0, stream>>>(X, Xb);
  transp_w<<<1024, 256, 0, stream>>>(W, Wt);
  gemm_gather<<<2048, 256, 0, stream>>>(Xb, Wt, ind, Y);
}

// Round 4
// 209.933 us; speedup vs baseline: 1.0552x; 1.0552x over previous
//
#include <hip/hip_runtime.h>

#define B_ 4
#define T_ 4096
#define I_ 512
#define E_ 16
#define K_ 1024
#define J_ 512

typedef unsigned short u16;
typedef unsigned int u32;
typedef __attribute__((ext_vector_type(4))) float floatx4;
typedef __attribute__((ext_vector_type(8))) short short8;
typedef __attribute__((ext_vector_type(4))) u16 u16x4;
typedef __attribute__((ext_vector_type(8))) u16 u16x8;

__device__ __forceinline__ u16 f2bf(float f) {
  unsigned int u = __float_as_uint(f);
  u += 0x7FFFu + ((u >> 16) & 1u);   // round-to-nearest-even
  return (u16)(u >> 16);
}

// async global->LDS, 16B per lane, dest = wave-uniform base + lane*16
__device__ __forceinline__ void gload16(const u16* g, u16* l) {
  __builtin_amdgcn_global_load_lds(
      (const __attribute__((address_space(1))) unsigned int*)(g),
      (__attribute__((address_space(3))) unsigned int*)(l),
      16, 0, 0);
}

// ---- prep (merged): blocks [0,1024) transpose W -> Wt bf16;
//                     blocks [1024,3072) convert X -> Xb bf16 ----------------
__global__ __launch_bounds__(256) void prep(const float* __restrict__ X,
                                            const float* __restrict__ W,
                                            u16* __restrict__ Xb,
                                            u16* __restrict__ Wt) {
  const int tid = threadIdx.x;
  const int blk = blockIdx.x;
  if (blk < 1024) {
    // W[e][i][j] fp32 -> Wt[e][j][i] bf16, 64x64 tiles
    __shared__ u16 tile[64][65];
    const int e  = blk >> 6;
    const int bi = (blk >> 3) & 7;
    const int bj = blk & 7;
    const int i0 = bi * 64, j0 = bj * 64;
#pragma unroll
    for (int p = 0; p < 4; ++p) {
      int r = p * 16 + (tid >> 4);
      int c = (tid & 15) * 4;
      floatx4 v = *(const floatx4*)(W + ((size_t)(e * I_ + i0 + r)) * J_ + j0 + c);
      tile[r][c + 0] = f2bf(v[0]);
      tile[r][c + 1] = f2bf(v[1]);
      tile[r][c + 2] = f2bf(v[2]);
      tile[r][c + 3] = f2bf(v[3]);
    }
    __syncthreads();
#pragma unroll
    for (int p = 0; p < 2; ++p) {
      int j = p * 32 + (tid >> 3);
      int ch = tid & 7;
      u16x8 o;
#pragma unroll
      for (int s = 0; s < 8; ++s) o[s] = tile[ch * 8 + s][j];
      *(u16x8*)(Wt + ((size_t)(e * J_ + j0 + j)) * I_ + i0 + ch * 8) = o;
    }
  } else {
    const int n4 = B_ * T_ * I_ / 4;
    int i = (blk - 1024) * 256 + tid;
    const int stride = 2048 * 256;
    for (; i < n4; i += stride) {
      floatx4 v = ((const floatx4*)X)[i];
      u16x4 o;
      o[0] = f2bf(v[0]); o[1] = f2bf(v[1]); o[2] = f2bf(v[2]); o[3] = f2bf(v[3]);
      ((u16x4*)Xb)[i] = o;
    }
  }
}

// ---- main: gather + bf16 MFMA GEMM -----------------------------------------
// Per block: 256 K-rows x 128 J-cols of one (b,e) pair. 4 waves as 2x2 of
// 128K x 64J wave-tiles; acc 4(j) x 8(k) floatx4. BK=64, 8 K-iterations.
// MFMA roles: A-op = Wt rows (M=J), B-op = gathered X rows (N=K) so D rows
// are consecutive j -> dwordx4 stores.
// LDS unpadded, XOR swizzle c_lds = c_glob ^ (row&7); staging via
// global_load_lds width=16 (wave-uniform base + lane*16).
__global__ __launch_bounds__(256, 2) void gemm_gather(
    const u16* __restrict__ Xb, const u16* __restrict__ Wt,
    const int* __restrict__ ind, float* __restrict__ Y) {
  __shared__ alignas(16) u16 Asf[256 * 64];   // gathered X rows: 32 KB
  __shared__ alignas(16) u16 Bsf[128 * 64];   // Wt rows:        16 KB

  const int tid = threadIdx.x;
  const int blk = blockIdx.x;          // 64 pairs * 4 n_t * 4 m_t = 1024
  const int m_t = blk & 3;             // K tile (fastest: B reuse adjacent)
  const int n_t = (blk >> 2) & 3;      // J tile
  const int be  = blk >> 4;            // b*E + e
  const int e = be & 15;
  const int b = be >> 4;

  const int lane = tid & 63;
  const int wave = tid >> 6;

  // staging mapping: one gload16 covers 8 rows x 8 chunks (16B each)
  const int lr = lane >> 3;                  // row within octet
  const int cg = (lane & 7) ^ lr;            // global chunk for this lane

  // A: 64 gathered rows per wave (8 instrs); keep 32-bit element offsets
  u32 aoff[8];
#pragma unroll
  for (int q = 0; q < 8; ++q) {
    const int r = wave * 64 + q * 8 + lr;
    const int t = ind[be * K_ + m_t * 256 + r];
    aoff[q] = (u32)(b * T_ + t) * I_ + cg * 8;
  }
  // B: 32 rows per wave (4 instrs), contiguous base
  const u16* bbase =
      Wt + ((size_t)(e * J_ + n_t * 128 + wave * 32 + lr)) * I_ + cg * 8;
  u16* ald = Asf + (wave * 64) * 64;
  u16* bld = Bsf + (wave * 32) * 64;

  const int wj = (wave & 1) * 64;      // J offset of wave-tile
  const int wk = (wave >> 1) * 128;    // K offset of wave-tile
  const int ml = lane & 15;
  const int quad = lane >> 4;

  floatx4 acc[4][8] = {};              // [iw = J blocks][ik = K blocks]

  for (int kk = 0; kk < I_; kk += 64) {
#pragma unroll
    for (int q = 0; q < 8; ++q) gload16(Xb + aoff[q] + kk, ald + q * 512);
#pragma unroll
    for (int q = 0; q < 4; ++q) gload16(bbase + q * 8 * I_ + kk, bld + q * 512);
    __syncthreads();                   // drains vmcnt -> tiles ready
#pragma unroll
    for (int s = 0; s < 2; ++s) {      // two K=32 sub-steps
      const int c = s * 4 + quad;      // 16B chunk in I-dim for this lane
      short8 wf[4];
#pragma unroll
      for (int i = 0; i < 4; ++i) {
        const int jr = wj + i * 16 + ml;
        wf[i] = *(const short8*)&Bsf[jr * 64 + ((c ^ (jr & 7)) * 8)];
      }
#pragma unroll
      for (int ik = 0; ik < 8; ++ik) {
        const int kr = wk + ik * 16 + ml;
        const short8 xf = *(const short8*)&Asf[kr * 64 + ((c ^ (kr & 7)) * 8)];
#pragma unroll
        for (int iw = 0; iw < 4; ++iw)
          acc[iw][ik] = __builtin_amdgcn_mfma_f32_16x16x32_bf16(
              wf[iw], xf, acc[iw][ik], 0, 0, 0);
      }
    }
    __syncthreads();
  }

  // epilogue: D row (m) = j = quad*4 + reg -> one float4 per tile
#pragma unroll
  for (int iw = 0; iw < 4; ++iw) {
    const int j0 = n_t * 128 + wj + iw * 16 + quad * 4;
#pragma unroll
    for (int ik = 0; ik < 8; ++ik) {
      const int k0 = m_t * 256 + wk + ik * 16 + ml;
      *(floatx4*)(Y + ((size_t)(be * K_ + k0)) * J_ + j0) = acc[iw][ik];
    }
  }
}

extern "C" void kernel_launch(void* const* d_in, const int* in_sizes, int n_in,
                              void* d_out, int out_size, void* d_ws,
                              size_t ws_size, hipStream_t stream) {
  const float* X  = (const float*)d_in[0];
  const int* ind  = (const int*)d_in[1];
  const float* W  = (const float*)d_in[2];
  float* Y = (float*)d_out;

  u16* Xb = (u16*)d_ws;                                        // 16 MiB
  u16* Wt = (u16*)((char*)d_ws + (size_t)B_ * T_ * I_ * 2);    // + 8 MiB

  prep<<<3072, 256, 0, stream>>>(X, W, Xb, Wt);
  gemm_gather<<<1024, 256, 0, stream>>>(Xb, Wt, ind, Y);
}